// Round 1
// baseline (217.376 us; speedup 1.0000x reference)
//
#include <hip/hip_runtime.h>
#include <stdint.h>

// Problem constants (fixed by setup_inputs): B=8, N=4096, d=256
#define N_NODES 4096
#define DMODEL  256
#define BATCH   8
#define NCOL    (BATCH * DMODEL)   // 2048 GEMM columns
#define KDIM    N_NODES            // 4096 reduction dim
#define INV_BND (1.0f / 8388608.0f) // 1/(B*N*d)

typedef __attribute__((ext_vector_type(8))) __bf16 bf16x8;
typedef __attribute__((ext_vector_type(8))) unsigned short ushort8;
typedef __attribute__((ext_vector_type(4))) float f32x4;

__device__ __forceinline__ void async_load16(const void* g, void* l) {
  // global -> LDS direct copy, 16B/lane; LDS dest = wave-uniform base + lane*16
  __builtin_amdgcn_global_load_lds(
      (const __attribute__((address_space(1))) void*)g,
      (__attribute__((address_space(3))) void*)l,
      16, 0, 0);
}

__device__ __forceinline__ f32x4 mfma_bf16(ushort8 a, ushort8 b, f32x4 c) {
  return __builtin_amdgcn_mfma_f32_16x16x32_bf16(
      __builtin_bit_cast(bf16x8, a), __builtin_bit_cast(bf16x8, b), c, 0, 0, 0);
}

// ---------------------------------------------------------------------------
// Kernel 1: adjacency(int32, NxN) -> A(bf16 bits, NxN) and w[i] = deg>0?1/deg:0
// ---------------------------------------------------------------------------
__global__ __launch_bounds__(256) void prep_adj(const int* __restrict__ adj,
                                                unsigned short* __restrict__ Abf,
                                                float* __restrict__ w) {
  const int i = blockIdx.x;
  const int tid = threadIdx.x;
  const int4* arow = (const int4*)(adj + (size_t)i * N_NODES);
  ushort4* orow = (ushort4*)(Abf + (size_t)i * N_NODES);
  int cnt = 0;
#pragma unroll
  for (int it = 0; it < 4; ++it) {
    int idx = it * 256 + tid;
    int4 v = arow[idx];
    ushort4 o;
    o.x = v.x ? 0x3F80u : 0u; cnt += (v.x != 0);
    o.y = v.y ? 0x3F80u : 0u; cnt += (v.y != 0);
    o.z = v.z ? 0x3F80u : 0u; cnt += (v.z != 0);
    o.w = v.w ? 0x3F80u : 0u; cnt += (v.w != 0);
    orow[idx] = o;
  }
#pragma unroll
  for (int off = 32; off > 0; off >>= 1) cnt += __shfl_down(cnt, off);
  __shared__ int wred[4];
  if ((tid & 63) == 0) wred[tid >> 6] = cnt;
  __syncthreads();
  if (tid == 0) {
    int total = wred[0] + wred[1] + wred[2] + wred[3];
    w[i] = (total > 0) ? (1.0f / (float)total) : 0.0f;
  }
}

// ---------------------------------------------------------------------------
// Kernel 2: S(B,N,d) f32 -> Bt(NCOL x K) bf16, Bt[b*256+dd][j] = S[b,j,dd]
// ---------------------------------------------------------------------------
__global__ __launch_bounds__(256) void trans_s(const float* __restrict__ S,
                                               unsigned short* __restrict__ Bt) {
  __shared__ float tile[32][33];
  const int b  = blockIdx.z;
  const int j0 = blockIdx.x * 32;
  const int d0 = blockIdx.y * 32;
  const int tx = threadIdx.x;  // 0..31
  const int ty = threadIdx.y;  // 0..7
  const float* Sb = S + (size_t)b * (N_NODES * DMODEL);
#pragma unroll
  for (int r = 0; r < 4; ++r) {
    int j = j0 + ty + r * 8;
    tile[ty + r * 8][tx] = Sb[(size_t)j * DMODEL + d0 + tx];
  }
  __syncthreads();
#pragma unroll
  for (int r = 0; r < 4; ++r) {
    int dd = d0 + ty + r * 8;
    float f = tile[tx][ty + r * 8];
    unsigned int u = __float_as_uint(f);
    unsigned int rnd = 0x7FFFu + ((u >> 16) & 1u);  // round-to-nearest-even
    Bt[(size_t)(b * DMODEL + dd) * KDIM + j0 + tx] = (unsigned short)((u + rnd) >> 16);
  }
}

// ---------------------------------------------------------------------------
// Kernel 3: C = A @ Bt^T (bf16 MFMA), fused divergence epilogue.
// 128x128 tile, BK=64, 4 waves each computing 64x64 via 4x4 16x16x32 MFMAs.
// ---------------------------------------------------------------------------
__global__ __launch_bounds__(256, 2) void gemm_div(const unsigned short* __restrict__ A,
                                                   const unsigned short* __restrict__ Bt,
                                                   const float* __restrict__ w,
                                                   const float* __restrict__ S,
                                                   float* __restrict__ out) {
  __shared__ unsigned short As[128 * 64];  // [row][k], k contiguous
  __shared__ unsigned short Bs[128 * 64];  // [col][k], k contiguous
  __shared__ float wsum[4];

  const int tid  = threadIdx.x;
  const int lane = tid & 63;
  const int wave = tid >> 6;
  const int wm   = wave >> 1;   // 0..1, M half
  const int wn   = wave & 1;    // 0..1, N half
  const int l16  = lane & 15;
  const int quad = lane >> 4;

  const int rowBase = blockIdx.x * 128;
  const int colBase = blockIdx.y * 128;

  const int srow = lane >> 3;       // row within 8-row chunk
  const int skb  = (lane & 7) * 8;  // element offset of this lane's 16B block

  f32x4 acc[4][4];
  const f32x4 zero = {0.f, 0.f, 0.f, 0.f};
#pragma unroll
  for (int i = 0; i < 4; ++i)
#pragma unroll
    for (int j = 0; j < 4; ++j) acc[i][j] = zero;

  const unsigned short* Ag = A  + (size_t)rowBase * KDIM;
  const unsigned short* Bg = Bt + (size_t)colBase * KDIM;

  for (int k0 = 0; k0 < KDIM; k0 += 64) {
    // ---- stage 32KB (A tile + B tile) via global_load_lds, 8 instrs/wave ----
#pragma unroll
    for (int c = 0; c < 4; ++c) {
      const int ch = wave * 4 + c;        // chunk 0..15, 8 rows each
      const int r  = ch * 8 + srow;
      async_load16(Ag + (size_t)r * KDIM + k0 + skb, &As[ch * 512]);
      async_load16(Bg + (size_t)r * KDIM + k0 + skb, &Bs[ch * 512]);
    }
    __syncthreads();  // compiler emits s_waitcnt vmcnt(0) before barrier

    // ---- compute: 2 k-steps of 32, 16 MFMA each ----
#pragma unroll
    for (int s = 0; s < 2; ++s) {
      ushort8 af[4], bfr[4];
#pragma unroll
      for (int mt = 0; mt < 4; ++mt)
        af[mt] = *(const ushort8*)&As[(wm * 64 + mt * 16 + l16) * 64 + s * 32 + quad * 8];
#pragma unroll
      for (int nt = 0; nt < 4; ++nt)
        bfr[nt] = *(const ushort8*)&Bs[(wn * 64 + nt * 16 + l16) * 64 + s * 32 + quad * 8];
#pragma unroll
      for (int mt = 0; mt < 4; ++mt)
#pragma unroll
        for (int nt = 0; nt < 4; ++nt)
          acc[mt][nt] = mfma_bf16(af[mt], bfr[nt], acc[mt][nt]);
    }
    __syncthreads();
  }

  // ---- fused epilogue: v = mask*(acc*w_i - S[b,i,dd]); sum v^2 ----
  // C/D layout: col = lane&15, row = quad*4 + reg   [m89/m91 verified]
  float local = 0.0f;
#pragma unroll
  for (int mt = 0; mt < 4; ++mt) {
    const int i0 = rowBase + wm * 64 + mt * 16 + quad * 4;
    float wr[4];
#pragma unroll
    for (int r = 0; r < 4; ++r) wr[r] = w[i0 + r];
#pragma unroll
    for (int nt = 0; nt < 4; ++nt) {
      const int col = colBase + wn * 64 + nt * 16 + l16;
      const int bb = col >> 8;
      const int dd = col & 255;
      const float* Sp = S + (size_t)bb * (N_NODES * DMODEL) + (size_t)i0 * DMODEL + dd;
#pragma unroll
      for (int r = 0; r < 4; ++r) {
        float v = acc[mt][nt][r] * wr[r] - Sp[(size_t)r * DMODEL];
        v = (wr[r] > 0.0f) ? v : 0.0f;  // isolated nodes contribute 0
        local += v * v;
      }
    }
  }

#pragma unroll
  for (int off = 32; off > 0; off >>= 1) local += __shfl_down(local, off);
  if (lane == 0) wsum[wave] = local;
  __syncthreads();
  if (tid == 0)
    atomicAdd(out, (wsum[0] + wsum[1] + wsum[2] + wsum[3]) * INV_BND);
}

// ---------------------------------------------------------------------------
extern "C" void kernel_launch(void* const* d_in, const int* in_sizes, int n_in,
                              void* d_out, int out_size, void* d_ws, size_t ws_size,
                              hipStream_t stream) {
  const float* S  = (const float*)d_in[0];   // (8, 4096, 256) f32
  const int* adj  = (const int*)d_in[1];     // (4096, 4096) i32
  float* out = (float*)d_out;                // scalar f32

  // ws layout: A_bf16 (32 MiB) | Bt_bf16 (16 MiB) | w (16 KiB)  => ~48 MiB
  unsigned short* Abf = (unsigned short*)d_ws;
  unsigned short* Btb = (unsigned short*)((char*)d_ws + (size_t)N_NODES * N_NODES * 2);
  float* w = (float*)((char*)d_ws + (size_t)N_NODES * N_NODES * 2 + (size_t)NCOL * KDIM * 2);

  hipMemsetAsync(d_out, 0, sizeof(float), stream);  // atomic accumulator target

  prep_adj<<<N_NODES, 256, 0, stream>>>(adj, Abf, w);

  dim3 tgrid(N_NODES / 32, DMODEL / 32, BATCH);
  trans_s<<<tgrid, dim3(32, 8, 1), 0, stream>>>(S, Btb);

  gemm_div<<<dim3(N_NODES / 128, NCOL / 128, 1), 256, 0, stream>>>(Abf, Btb, w, S, out);
}

// Round 2
// 186.627 us; speedup vs baseline: 1.1648x; 1.1648x over previous
//
#include <hip/hip_runtime.h>
#include <stdint.h>

// Problem constants (fixed by setup_inputs): B=8, N=4096, d=256
#define N_NODES 4096
#define DMODEL  256
#define BATCH   8
#define NCOL    (BATCH * DMODEL)   // 2048 GEMM columns
#define KDIM    N_NODES            // 4096 reduction dim
#define INV_BND (1.0f / 8388608.0f) // 1/(B*N*d)

typedef __attribute__((ext_vector_type(8))) __bf16 bf16x8;
typedef __attribute__((ext_vector_type(8))) unsigned short ushort8;
typedef __attribute__((ext_vector_type(4))) float f32x4;

__device__ __forceinline__ void async_load16(const void* g, void* l) {
  __builtin_amdgcn_global_load_lds(
      (const __attribute__((address_space(1))) void*)g,
      (__attribute__((address_space(3))) void*)l,
      16, 0, 0);
}

__device__ __forceinline__ f32x4 mfma_bf16(ushort8 a, ushort8 b, f32x4 c) {
  return __builtin_amdgcn_mfma_f32_16x16x32_bf16(
      __builtin_bit_cast(bf16x8, a), __builtin_bit_cast(bf16x8, b), c, 0, 0, 0);
}

__device__ __forceinline__ unsigned short f32_to_bf16_rne(float f) {
  unsigned int u = __float_as_uint(f);
  unsigned int rnd = 0x7FFFu + ((u >> 16) & 1u);
  return (unsigned short)((u + rnd) >> 16);
}

// ---------------------------------------------------------------------------
// Kernel 1: adjacency(int32, NxN) -> A(bf16 bits, NxN) and w[i] = deg>0?1/deg:0
// 16 ints/thread, ushort8 (16B) stores.
// ---------------------------------------------------------------------------
__global__ __launch_bounds__(256) void prep_adj(const int* __restrict__ adj,
                                                unsigned short* __restrict__ Abf,
                                                float* __restrict__ w) {
  const int i = blockIdx.x;
  const int tid = threadIdx.x;
  const int4* arow = (const int4*)(adj + (size_t)i * N_NODES);
  ushort8* orow = (ushort8*)(Abf + (size_t)i * N_NODES);  // 512 per row
  int cnt = 0;
#pragma unroll
  for (int it = 0; it < 2; ++it) {
    const int b4 = it * 512 + tid * 2;  // int4 index (1024 per row)
    int4 a = arow[b4];
    int4 b = arow[b4 + 1];
    ushort8 o;
    o[0] = a.x ? 0x3F80u : 0u; cnt += (a.x != 0);
    o[1] = a.y ? 0x3F80u : 0u; cnt += (a.y != 0);
    o[2] = a.z ? 0x3F80u : 0u; cnt += (a.z != 0);
    o[3] = a.w ? 0x3F80u : 0u; cnt += (a.w != 0);
    o[4] = b.x ? 0x3F80u : 0u; cnt += (b.x != 0);
    o[5] = b.y ? 0x3F80u : 0u; cnt += (b.y != 0);
    o[6] = b.z ? 0x3F80u : 0u; cnt += (b.z != 0);
    o[7] = b.w ? 0x3F80u : 0u; cnt += (b.w != 0);
    orow[it * 256 + tid] = o;
  }
#pragma unroll
  for (int off = 32; off > 0; off >>= 1) cnt += __shfl_down(cnt, off);
  __shared__ int wred[4];
  if ((tid & 63) == 0) wred[tid >> 6] = cnt;
  __syncthreads();
  if (tid == 0) {
    int total = wred[0] + wred[1] + wred[2] + wred[3];
    w[i] = (total > 0) ? (1.0f / (float)total) : 0.0f;
  }
}

// ---------------------------------------------------------------------------
// Kernel 2: S(B,N,d) f32 -> Bt(NCOL x K) bf16, Bt[b*256+dd][j] = S[b,j,dd]
// 64(j) x 32(dd) tile; float4 global reads, ushort8 global stores.
// ---------------------------------------------------------------------------
__global__ __launch_bounds__(256) void trans_s(const float* __restrict__ S,
                                               unsigned short* __restrict__ Bt) {
  __shared__ float tile[64][36];  // pad 36: row start stays 16B-aligned
  const int b  = blockIdx.z;
  const int j0 = blockIdx.x * 64;
  const int d0 = blockIdx.y * 32;
  const int t  = threadIdx.x;
  const float* Sb = S + (size_t)b * (N_NODES * DMODEL);

  const int c  = t & 7;   // float4 index within 32-float row
  const int jr = t >> 3;  // 0..31
#pragma unroll
  for (int p = 0; p < 2; ++p) {
    const int j = jr + p * 32;
    float4 v = *(const float4*)&Sb[(size_t)(j0 + j) * DMODEL + d0 + c * 4];
    *(float4*)&tile[j][c * 4] = v;
  }
  __syncthreads();

  const int dr = t >> 3;        // 0..31 output row (dd)
  const int jt = (t & 7) * 8;   // 8-j chunk
  ushort8 o;
#pragma unroll
  for (int r = 0; r < 8; ++r) o[r] = f32_to_bf16_rne(tile[jt + r][dr]);
  *(ushort8*)&Bt[(size_t)(b * DMODEL + d0 + dr) * KDIM + j0 + jt] = o;
}

// ---------------------------------------------------------------------------
// Kernel 3: C = A @ Bt^T (bf16 MFMA), fused divergence epilogue.
// 128x128 tile, in-block split-K: 8 waves, groups of 4 each own half the
// K-strides with a private 32KB LDS double-half; XOR-swizzled k-chunks kill
// ds_read bank conflicts. Group 1 stashes acc; group 0 combines + epilogue.
// ---------------------------------------------------------------------------
__global__ __launch_bounds__(512, 4) void gemm_div(const unsigned short* __restrict__ A,
                                                   const unsigned short* __restrict__ Bt,
                                                   const float* __restrict__ w,
                                                   const float* __restrict__ S,
                                                   float* __restrict__ out) {
  __shared__ unsigned short lds[32768];  // 64 KB: As0|As1|Bs0|Bs1, 16KB each
  __shared__ float wsum[4];

  const int tid  = threadIdx.x;
  const int lane = tid & 63;
  const int wave = tid >> 6;    // 0..7
  const int grp  = wave >> 2;   // K-half owner
  const int w4   = wave & 3;
  const int wm   = w4 >> 1;
  const int wn   = w4 & 1;
  const int l16  = lane & 15;
  const int quad = lane >> 4;

  unsigned short* As = lds + grp * 8192;          // [row 0..127][k 0..63]
  unsigned short* Bs = lds + 16384 + grp * 8192;  // [col 0..127][k 0..63]

  const int rowBase = blockIdx.x * 128;
  const int colBase = blockIdx.y * 128;

  const int srow = lane >> 3;                      // 0..7
  const int kc   = ((lane & 7) ^ srow) * 8;        // swizzled source k-chunk

  f32x4 acc[4][4];
  const f32x4 zero = {0.f, 0.f, 0.f, 0.f};
#pragma unroll
  for (int i = 0; i < 4; ++i)
#pragma unroll
    for (int j = 0; j < 4; ++j) acc[i][j] = zero;

  const unsigned short* Ag = A  + (size_t)rowBase * KDIM;
  const unsigned short* Bg = Bt + (size_t)colBase * KDIM;

  for (int k0 = grp * 64; k0 < KDIM; k0 += 128) {
    // stage this group's 32KB tile: LDS[r][p] holds global chunk p^(r&7)
#pragma unroll
    for (int c = 0; c < 4; ++c) {
      const int ch = w4 * 4 + c;      // chunk 0..15, 8 rows each
      const int r  = ch * 8 + srow;
      async_load16(Ag + (size_t)r * KDIM + k0 + kc, &As[ch * 512]);
      async_load16(Bg + (size_t)r * KDIM + k0 + kc, &Bs[ch * 512]);
    }
    __syncthreads();

#pragma unroll
    for (int s = 0; s < 2; ++s) {
      const int pofs = ((s * 4 + quad) ^ (l16 & 7)) * 8;  // de-swizzle
      ushort8 af[4], bfr[4];
#pragma unroll
      for (int mt = 0; mt < 4; ++mt)
        af[mt] = *(const ushort8*)&As[(wm * 64 + mt * 16 + l16) * 64 + pofs];
#pragma unroll
      for (int nt = 0; nt < 4; ++nt)
        bfr[nt] = *(const ushort8*)&Bs[(wn * 64 + nt * 16 + l16) * 64 + pofs];
#pragma unroll
      for (int mt = 0; mt < 4; ++mt)
#pragma unroll
        for (int nt = 0; nt < 4; ++nt)
          acc[mt][nt] = mfma_bf16(af[mt], bfr[nt], acc[mt][nt]);
    }
    __syncthreads();
  }

  // ---- combine the two K-halves via LDS stash ----
  float* stash = (float*)lds;  // 16384 floats = 64 KB
  if (grp == 1) {
#pragma unroll
    for (int mt = 0; mt < 4; ++mt)
#pragma unroll
      for (int nt = 0; nt < 4; ++nt)
#pragma unroll
        for (int r = 0; r < 4; ++r)
          stash[w4 * 4096 + (mt * 4 + nt) * 256 + (quad * 4 + r) * 16 + l16] =
              acc[mt][nt][r];
  }
  __syncthreads();

  // ---- fused epilogue (group 0): v = mask*(C*w_i - S); sum v^2 ----
  // C/D layout: col = lane&15, row = quad*4 + reg
  float local = 0.0f;
  if (grp == 0) {
#pragma unroll
    for (int mt = 0; mt < 4; ++mt) {
      const int i0 = rowBase + wm * 64 + mt * 16 + quad * 4;
      float wr[4];
#pragma unroll
      for (int r = 0; r < 4; ++r) wr[r] = w[i0 + r];
#pragma unroll
      for (int nt = 0; nt < 4; ++nt) {
        const int col = colBase + wn * 64 + nt * 16 + l16;
        const int bb = col >> 8;
        const int dd = col & 255;
        const float* Sp = S + (size_t)bb * (N_NODES * DMODEL) + (size_t)i0 * DMODEL + dd;
#pragma unroll
        for (int r = 0; r < 4; ++r) {
          float cs = acc[mt][nt][r] +
                     stash[w4 * 4096 + (mt * 4 + nt) * 256 + (quad * 4 + r) * 16 + l16];
          float v = cs * wr[r] - Sp[(size_t)r * DMODEL];
          v = (wr[r] > 0.0f) ? v : 0.0f;
          local += v * v;
        }
      }
    }
#pragma unroll
    for (int off = 32; off > 0; off >>= 1) local += __shfl_down(local, off);
    if (lane == 0) wsum[w4] = local;
  }
  __syncthreads();
  if (tid == 0)
    atomicAdd(out, (wsum[0] + wsum[1] + wsum[2] + wsum[3]) * INV_BND);
}

// ---------------------------------------------------------------------------
extern "C" void kernel_launch(void* const* d_in, const int* in_sizes, int n_in,
                              void* d_out, int out_size, void* d_ws, size_t ws_size,
                              hipStream_t stream) {
  const float* S  = (const float*)d_in[0];   // (8, 4096, 256) f32
  const int* adj  = (const int*)d_in[1];     // (4096, 4096) i32
  float* out = (float*)d_out;                // scalar f32

  // ws layout: A_bf16 (32 MiB) | Bt_bf16 (16 MiB) | w (16 KiB)
  unsigned short* Abf = (unsigned short*)d_ws;
  unsigned short* Btb = (unsigned short*)((char*)d_ws + (size_t)N_NODES * N_NODES * 2);
  float* w = (float*)((char*)d_ws + (size_t)N_NODES * N_NODES * 2 + (size_t)NCOL * KDIM * 2);

  hipMemsetAsync(d_out, 0, sizeof(float), stream);

  prep_adj<<<N_NODES, 256, 0, stream>>>(adj, Abf, w);

  dim3 tgrid(N_NODES / 64, DMODEL / 32, BATCH);
  trans_s<<<tgrid, 256, 0, stream>>>(S, Btb);

  gemm_div<<<dim3(N_NODES / 128, NCOL / 128, 1), 512, 0, stream>>>(Abf, Btb, w, S, out);
}

// Round 3
// 165.263 us; speedup vs baseline: 1.3153x; 1.1293x over previous
//
#include <hip/hip_runtime.h>
#include <stdint.h>

// Problem constants (fixed by setup_inputs): B=8, N=4096, d=256
#define N_NODES 4096
#define DMODEL  256
#define BATCH   8
#define NCOL    (BATCH * DMODEL)   // 2048 GEMM columns
#define KDIM    N_NODES            // 4096 reduction dim
#define INV_BND (1.0f / 8388608.0f) // 1/(B*N*d)

typedef __attribute__((ext_vector_type(8))) int   int32x8;
typedef __attribute__((ext_vector_type(4))) float f32x4;

__device__ __forceinline__ void async_load16(const void* g, void* l) {
  __builtin_amdgcn_global_load_lds(
      (const __attribute__((address_space(1))) void*)g,
      (__attribute__((address_space(3))) void*)l, 16, 0, 0);
}

// MX-scaled fp8 MFMA with unit scales (e8m0 byte 127 = 2^0; all bytes 127 so
// any opsel byte-select reads 1.0). cbsz/blgp = 0 -> both operands e4m3.
__device__ __forceinline__ f32x4 mfma_mx(int32x8 a, int32x8 b, f32x4 c) {
  return __builtin_amdgcn_mfma_scale_f32_16x16x128_f8f6f4(
      a, b, c, 0, 0, 0, 0x7F7F7F7Fu, 0, 0x7F7F7F7Fu);
}

// ---------------------------------------------------------------------------
// Fat prep kernel (single dispatch):
//  blocks [0, 4096):    adjacency(int32) -> A8 (fp8 e4m3 {0,1.0}) + w[i]
//  blocks [4096, 8192): S(B,N,d) f32 -> B8 (NCOL x K fp8), transposed
//  block 0 also zeroes *out (runs before gemm in stream order).
// ---------------------------------------------------------------------------
__global__ __launch_bounds__(256) void fat_prep(const int* __restrict__ adj,
                                                const float* __restrict__ S,
                                                unsigned char* __restrict__ A8,
                                                unsigned char* __restrict__ B8,
                                                float* __restrict__ w,
                                                float* __restrict__ out) {
  __shared__ float tile[64][36];
  __shared__ int wred[4];
  const int bx = blockIdx.x;
  const int t  = threadIdx.x;

  if (bx < N_NODES) {
    // ---- adjacency row bx: int32 -> fp8 (1.0 = 0x38), count degree ----
    if (bx == 0 && t == 0) *out = 0.0f;
    const int4* arow = (const int4*)(adj + (size_t)bx * N_NODES);
    int cnt = 0;
    unsigned int b[4];
#pragma unroll
    for (int q = 0; q < 4; ++q) {
      int4 a = arow[t * 4 + q];
      unsigned int p = 0;
      p |= a.x ? 0x38u       : 0u; cnt += (a.x != 0);
      p |= a.y ? 0x3800u     : 0u; cnt += (a.y != 0);
      p |= a.z ? 0x380000u   : 0u; cnt += (a.z != 0);
      p |= a.w ? 0x38000000u : 0u; cnt += (a.w != 0);
      b[q] = p;
    }
    uint4 o; o.x = b[0]; o.y = b[1]; o.z = b[2]; o.w = b[3];
    ((uint4*)(A8 + (size_t)bx * N_NODES))[t] = o;  // 16B store, contiguous
#pragma unroll
    for (int off = 32; off > 0; off >>= 1) cnt += __shfl_down(cnt, off);
    if ((t & 63) == 0) wred[t >> 6] = cnt;
    __syncthreads();
    if (t == 0) {
      int total = wred[0] + wred[1] + wred[2] + wred[3];
      w[bx] = (total > 0) ? (1.0f / (float)total) : 0.0f;
    }
  } else {
    // ---- transpose+quantize: B8[b*256+dd][j] = fp8(S[b,j,dd]) ----
    const int bt = bx - N_NODES;
    const int j0 = (bt & 63) * 64;
    const int d0 = ((bt >> 6) & 7) * 32;
    const int bb = bt >> 9;
    const float* Sb = S + (size_t)bb * (N_NODES * DMODEL);

    const int c  = t & 7;   // float4 index within 32-float row
    const int jr = t >> 3;  // 0..31
#pragma unroll
    for (int p = 0; p < 2; ++p) {
      const int j = jr + p * 32;
      float4 v = *(const float4*)&Sb[(size_t)(j0 + j) * DMODEL + d0 + c * 4];
      *(float4*)&tile[j][c * 4] = v;
    }
    __syncthreads();

    const int dr = t >> 3;        // 0..31 output dd-row
    const int jt = (t & 7) * 8;   // 8-j chunk
    int lo = __builtin_amdgcn_cvt_pk_fp8_f32(tile[jt + 0][dr], tile[jt + 1][dr], 0, false);
    lo     = __builtin_amdgcn_cvt_pk_fp8_f32(tile[jt + 2][dr], tile[jt + 3][dr], lo, true);
    int hi = __builtin_amdgcn_cvt_pk_fp8_f32(tile[jt + 4][dr], tile[jt + 5][dr], 0, false);
    hi     = __builtin_amdgcn_cvt_pk_fp8_f32(tile[jt + 6][dr], tile[jt + 7][dr], hi, true);
    uint2 o; o.x = (unsigned int)lo; o.y = (unsigned int)hi;
    *(uint2*)&B8[(size_t)(bb * DMODEL + d0 + dr) * KDIM + j0 + jt] = o;  // 8B store
  }
}

// ---------------------------------------------------------------------------
// GEMM C = A @ Bt^T in MX-fp8 (16x16x128, unit scales), fused divergence
// epilogue. 128x128 tile, BK=128, in-block split-K (2 groups x 4 waves),
// XOR-swizzled 16B k-chunks in LDS (free 2-way conflicts only).
// ---------------------------------------------------------------------------
__global__ __launch_bounds__(512, 4) void gemm_div(const unsigned char* __restrict__ A8,
                                                   const unsigned char* __restrict__ B8,
                                                   const float* __restrict__ w,
                                                   const float* __restrict__ S,
                                                   float* __restrict__ out) {
  __shared__ unsigned char lds[65536];  // As0|As1|Bs0|Bs1, 16KB each
  __shared__ float wsum[4];

  const int tid  = threadIdx.x;
  const int lane = tid & 63;
  const int wave = tid >> 6;    // 0..7
  const int grp  = wave >> 2;   // K-half owner
  const int w4   = wave & 3;
  const int wm   = w4 >> 1;
  const int wn   = w4 & 1;
  const int l16  = lane & 15;
  const int quad = lane >> 4;

  unsigned char* As = lds + grp * 16384;          // [row 0..127][k-chunk 0..7]
  unsigned char* Bs = lds + 32768 + grp * 16384;  // [col 0..127][k-chunk 0..7]

  const int rowBase = blockIdx.x * 128;
  const int colBase = blockIdx.y * 128;

  const int srow = lane >> 3;                       // 0..7 (row mod 8)
  const int kc   = ((lane & 7) ^ srow) * 16;        // swizzled source chunk (bytes)

  f32x4 acc[4][4];
  const f32x4 zero = {0.f, 0.f, 0.f, 0.f};
#pragma unroll
  for (int i = 0; i < 4; ++i)
#pragma unroll
    for (int j = 0; j < 4; ++j) acc[i][j] = zero;

  const unsigned char* Ag = A8 + (size_t)rowBase * KDIM;
  const unsigned char* Bg = B8 + (size_t)colBase * KDIM;

  for (int k0 = grp * 128; k0 < KDIM; k0 += 256) {
    // stage this group's 32KB: LDS row r, position p holds global chunk p^(r&7)
#pragma unroll
    for (int c = 0; c < 4; ++c) {
      const int r = (w4 * 4 + c) * 8 + srow;
      async_load16(Ag + (size_t)r * KDIM + k0 + kc, As + (w4 * 4 + c) * 1024);
      async_load16(Bg + (size_t)r * KDIM + k0 + kc, Bs + (w4 * 4 + c) * 1024);
    }
    __syncthreads();

    // fragments: lane needs k-bytes [quad*32, quad*32+32) = global chunks 2q,2q+1
    int32x8 bfrag[4];
#pragma unroll
    for (int nt = 0; nt < 4; ++nt) {
      const int r = wn * 64 + nt * 16 + l16;
      const unsigned char* rp = Bs + r * 128;
      const int x = r & 7;
      int4 lo = *(const int4*)(rp + (((2 * quad)    ) ^ x) * 16);
      int4 hi = *(const int4*)(rp + (((2 * quad) | 1) ^ x) * 16);
      bfrag[nt][0] = lo.x; bfrag[nt][1] = lo.y; bfrag[nt][2] = lo.z; bfrag[nt][3] = lo.w;
      bfrag[nt][4] = hi.x; bfrag[nt][5] = hi.y; bfrag[nt][6] = hi.z; bfrag[nt][7] = hi.w;
    }
#pragma unroll
    for (int mt = 0; mt < 4; ++mt) {
      const int r = wm * 64 + mt * 16 + l16;
      const unsigned char* rp = As + r * 128;
      const int x = r & 7;
      int4 lo = *(const int4*)(rp + (((2 * quad)    ) ^ x) * 16);
      int4 hi = *(const int4*)(rp + (((2 * quad) | 1) ^ x) * 16);
      int32x8 a;
      a[0] = lo.x; a[1] = lo.y; a[2] = lo.z; a[3] = lo.w;
      a[4] = hi.x; a[5] = hi.y; a[6] = hi.z; a[7] = hi.w;
#pragma unroll
      for (int nt = 0; nt < 4; ++nt)
        acc[mt][nt] = mfma_mx(a, bfrag[nt], acc[mt][nt]);
    }
    __syncthreads();
  }

  // ---- combine the two K-halves via LDS stash ----
  float* stash = (float*)lds;  // 16384 floats = 64 KB
  if (grp == 1) {
#pragma unroll
    for (int mt = 0; mt < 4; ++mt)
#pragma unroll
      for (int nt = 0; nt < 4; ++nt)
#pragma unroll
        for (int r = 0; r < 4; ++r)
          stash[w4 * 4096 + (mt * 4 + nt) * 256 + (quad * 4 + r) * 16 + l16] =
              acc[mt][nt][r];
  }
  __syncthreads();

  // ---- fused epilogue (group 0): v = mask*(C*w_i - S); sum v^2 ----
  // C/D layout (shape-determined): col = lane&15, row = quad*4 + reg
  float local = 0.0f;
  if (grp == 0) {
#pragma unroll
    for (int mt = 0; mt < 4; ++mt) {
      const int i0 = rowBase + wm * 64 + mt * 16 + quad * 4;
      float wr[4];
#pragma unroll
      for (int r = 0; r < 4; ++r) wr[r] = w[i0 + r];
#pragma unroll
      for (int nt = 0; nt < 4; ++nt) {
        const int col = colBase + wn * 64 + nt * 16 + l16;
        const int bb = col >> 8;
        const int dd = col & 255;
        const float* Sp = S + (size_t)bb * (N_NODES * DMODEL) + (size_t)i0 * DMODEL + dd;
#pragma unroll
        for (int r = 0; r < 4; ++r) {
          float cs = acc[mt][nt][r] +
                     stash[w4 * 4096 + (mt * 4 + nt) * 256 + (quad * 4 + r) * 16 + l16];
          float v = cs * wr[r] - Sp[(size_t)r * DMODEL];
          v = (wr[r] > 0.0f) ? v : 0.0f;
          local += v * v;
        }
      }
    }
#pragma unroll
    for (int off = 32; off > 0; off >>= 1) local += __shfl_down(local, off);
    if (lane == 0) wsum[w4] = local;
  }
  __syncthreads();
  if (tid == 0)
    atomicAdd(out, (wsum[0] + wsum[1] + wsum[2] + wsum[3]) * INV_BND);
}

// ---------------------------------------------------------------------------
extern "C" void kernel_launch(void* const* d_in, const int* in_sizes, int n_in,
                              void* d_out, int out_size, void* d_ws, size_t ws_size,
                              hipStream_t stream) {
  const float* S  = (const float*)d_in[0];   // (8, 4096, 256) f32
  const int* adj  = (const int*)d_in[1];     // (4096, 4096) i32
  float* out = (float*)d_out;                // scalar f32

  // ws layout: A8 fp8 (16 MiB) | B8 fp8 (8 MiB) | w (16 KiB)
  unsigned char* A8 = (unsigned char*)d_ws;
  unsigned char* B8 = (unsigned char*)d_ws + (size_t)N_NODES * N_NODES;
  float* w = (float*)((char*)d_ws + (size_t)N_NODES * N_NODES + (size_t)NCOL * KDIM);

  // single prep dispatch: adj-blocks [0,4096), transpose-blocks [4096,8192)
  fat_prep<<<N_NODES + N_NODES / 64 * (DMODEL / 32) * BATCH, 256, 0, stream>>>(
      adj, S, A8, B8, w, out);

  gemm_div<<<dim3(N_NODES / 128, NCOL / 128, 1), 512, 0, stream>>>(A8, B8, w, S, out);
}

// Round 4
// 163.269 us; speedup vs baseline: 1.3314x; 1.0122x over previous
//
#include <hip/hip_runtime.h>
#include <stdint.h>

// Problem constants (fixed by setup_inputs): B=8, N=4096, d=256
#define N_NODES 4096
#define DMODEL  256
#define BATCH   8
#define NCOL    (BATCH * DMODEL)   // 2048 GEMM columns
#define KDIM    N_NODES            // 4096 reduction dim
#define INV_BND (1.0f / 8388608.0f) // 1/(B*N*d)

typedef __attribute__((ext_vector_type(8))) int   int32x8;
typedef __attribute__((ext_vector_type(4))) float f32x4;

__device__ __forceinline__ void async_load16(const void* g, void* l) {
  __builtin_amdgcn_global_load_lds(
      (const __attribute__((address_space(1))) void*)g,
      (__attribute__((address_space(3))) void*)l, 16, 0, 0);
}

// MX-scaled fp8 MFMA with unit scales (e8m0 byte 127 = 2^0).
__device__ __forceinline__ f32x4 mfma_mx(int32x8 a, int32x8 b, f32x4 c) {
  return __builtin_amdgcn_mfma_scale_f32_16x16x128_f8f6f4(
      a, b, c, 0, 0, 0, 0x7F7F7F7Fu, 0, 0x7F7F7F7Fu);
}

// ---------------------------------------------------------------------------
// Fat prep kernel (single dispatch):
//  blocks [0, 4096):    adjacency(int32) -> A8 (fp8 e4m3 {0,1.0}) + w[i]
//  blocks [4096, 6144): S(B,N,d) f32 -> B8 (NCOL x K fp8), transposed
//  block 0 also zeroes *out (completes before gemm in stream order).
// ---------------------------------------------------------------------------
__global__ __launch_bounds__(256) void fat_prep(const int* __restrict__ adj,
                                                const float* __restrict__ S,
                                                unsigned char* __restrict__ A8,
                                                unsigned char* __restrict__ B8,
                                                float* __restrict__ w,
                                                float* __restrict__ out) {
  __shared__ float tile[128][36];
  __shared__ int wred[4];
  const int bx = blockIdx.x;
  const int t  = threadIdx.x;

  if (bx < N_NODES) {
    // ---- adjacency row bx: int32 -> fp8 (1.0 = 0x38), count degree ----
    if (bx == 0 && t == 0) *out = 0.0f;
    const int4* arow = (const int4*)(adj + (size_t)bx * N_NODES);
    int cnt = 0;
    unsigned int b[4];
#pragma unroll
    for (int q = 0; q < 4; ++q) {
      int4 a = arow[t * 4 + q];
      unsigned int p = 0;
      p |= a.x ? 0x38u       : 0u; cnt += (a.x != 0);
      p |= a.y ? 0x3800u     : 0u; cnt += (a.y != 0);
      p |= a.z ? 0x380000u   : 0u; cnt += (a.z != 0);
      p |= a.w ? 0x38000000u : 0u; cnt += (a.w != 0);
      b[q] = p;
    }
    uint4 o; o.x = b[0]; o.y = b[1]; o.z = b[2]; o.w = b[3];
    ((uint4*)(A8 + (size_t)bx * N_NODES))[t] = o;
#pragma unroll
    for (int off = 32; off > 0; off >>= 1) cnt += __shfl_down(cnt, off);
    if ((t & 63) == 0) wred[t >> 6] = cnt;
    __syncthreads();
    if (t == 0) {
      int total = wred[0] + wred[1] + wred[2] + wred[3];
      w[bx] = (total > 0) ? (1.0f / (float)total) : 0.0f;
    }
  } else {
    // ---- transpose+quantize: B8[b*256+dd][j] = fp8(S[b,j,dd]) ----
    // 128(j) x 32(dd) tile; float4 reads, uint4 (16B) stores.
    const int bt = bx - N_NODES;
    const int j0 = (bt & 31) * 128;
    const int d0 = ((bt >> 5) & 7) * 32;
    const int bb = bt >> 8;
    const float* Sb = S + (size_t)bb * (N_NODES * DMODEL);

#pragma unroll
    for (int p = 0; p < 4; ++p) {
      const int idx = p * 256 + t;   // 0..1023
      const int j = idx >> 3;        // 0..127
      const int c = idx & 7;         // float4 col
      float4 v = *(const float4*)&Sb[(size_t)(j0 + j) * DMODEL + d0 + c * 4];
      *(float4*)&tile[j][c * 4] = v;
    }
    __syncthreads();

    const int dr = t >> 3;          // 0..31 output dd-row
    const int jt = (t & 7) * 16;    // 16-j chunk
    uint4 o;
    {
      int v0 = __builtin_amdgcn_cvt_pk_fp8_f32(tile[jt + 0][dr], tile[jt + 1][dr], 0, false);
      v0     = __builtin_amdgcn_cvt_pk_fp8_f32(tile[jt + 2][dr], tile[jt + 3][dr], v0, true);
      int v1 = __builtin_amdgcn_cvt_pk_fp8_f32(tile[jt + 4][dr], tile[jt + 5][dr], 0, false);
      v1     = __builtin_amdgcn_cvt_pk_fp8_f32(tile[jt + 6][dr], tile[jt + 7][dr], v1, true);
      int v2 = __builtin_amdgcn_cvt_pk_fp8_f32(tile[jt + 8][dr], tile[jt + 9][dr], 0, false);
      v2     = __builtin_amdgcn_cvt_pk_fp8_f32(tile[jt +10][dr], tile[jt +11][dr], v2, true);
      int v3 = __builtin_amdgcn_cvt_pk_fp8_f32(tile[jt +12][dr], tile[jt +13][dr], 0, false);
      v3     = __builtin_amdgcn_cvt_pk_fp8_f32(tile[jt +14][dr], tile[jt +15][dr], v3, true);
      o.x = (unsigned int)v0; o.y = (unsigned int)v1;
      o.z = (unsigned int)v2; o.w = (unsigned int)v3;
    }
    *(uint4*)&B8[(size_t)(bb * DMODEL + d0 + dr) * KDIM + j0 + jt] = o;
  }
}

// ---------------------------------------------------------------------------
// GEMM C = A @ Bt^T in MX-fp8 (16x16x128, unit scales), fused divergence
// epilogue. 128x128 tile, BK=128, 256 threads (4 waves, each a 64x64
// quadrant), 32KB LDS -> 4 blocks/CU with independent barrier domains.
// XOR-swizzled 16B k-chunks: all LDS accesses are <=2-way conflicts (free).
// ---------------------------------------------------------------------------
__global__ __launch_bounds__(256, 4) void gemm_div(const unsigned char* __restrict__ A8,
                                                   const unsigned char* __restrict__ B8,
                                                   const float* __restrict__ w,
                                                   const float* __restrict__ S,
                                                   float* __restrict__ out) {
  __shared__ unsigned char As[16384];  // [row 0..127][k-byte 0..127], swizzled
  __shared__ unsigned char Bs[16384];  // [col 0..127][k-byte 0..127], swizzled
  __shared__ float wsum[4];

  const int tid  = threadIdx.x;
  const int lane = tid & 63;
  const int wave = tid >> 6;    // 0..3
  const int wm   = wave >> 1;
  const int wn   = wave & 1;
  const int l16  = lane & 15;
  const int quad = lane >> 4;

  const int rowBase = blockIdx.x * 128;
  const int colBase = blockIdx.y * 128;

  const int srow = lane >> 3;                 // 0..7 (row mod 8)
  const int kc   = ((lane & 7) ^ srow) * 16;  // swizzled source chunk (bytes)

  f32x4 acc[4][4];
  const f32x4 zero = {0.f, 0.f, 0.f, 0.f};
#pragma unroll
  for (int i = 0; i < 4; ++i)
#pragma unroll
    for (int j = 0; j < 4; ++j) acc[i][j] = zero;

  const unsigned char* Ag = A8 + (size_t)rowBase * KDIM;
  const unsigned char* Bg = B8 + (size_t)colBase * KDIM;

  for (int k0 = 0; k0 < KDIM; k0 += 128) {
    // stage 32KB: LDS row r, position p holds global chunk p^(r&7)
#pragma unroll
    for (int c = 0; c < 4; ++c) {
      const int ch = wave * 4 + c;   // 0..15, 8 rows each
      const int r  = ch * 8 + srow;
      async_load16(Ag + (size_t)r * KDIM + k0 + kc, As + ch * 1024);
      async_load16(Bg + (size_t)r * KDIM + k0 + kc, Bs + ch * 1024);
    }
    __syncthreads();

    // fragments: lane needs k-bytes [quad*32, quad*32+32) = chunks 2q, 2q+1
    int32x8 bfrag[4];
#pragma unroll
    for (int nt = 0; nt < 4; ++nt) {
      const int r = wn * 64 + nt * 16 + l16;
      const unsigned char* rp = Bs + r * 128;
      const int x = r & 7;
      int4 lo = *(const int4*)(rp + (((2 * quad)    ) ^ x) * 16);
      int4 hi = *(const int4*)(rp + (((2 * quad) | 1) ^ x) * 16);
      bfrag[nt][0] = lo.x; bfrag[nt][1] = lo.y; bfrag[nt][2] = lo.z; bfrag[nt][3] = lo.w;
      bfrag[nt][4] = hi.x; bfrag[nt][5] = hi.y; bfrag[nt][6] = hi.z; bfrag[nt][7] = hi.w;
    }
#pragma unroll
    for (int mt = 0; mt < 4; ++mt) {
      const int r = wm * 64 + mt * 16 + l16;
      const unsigned char* rp = As + r * 128;
      const int x = r & 7;
      int4 lo = *(const int4*)(rp + (((2 * quad)    ) ^ x) * 16);
      int4 hi = *(const int4*)(rp + (((2 * quad) | 1) ^ x) * 16);
      int32x8 a;
      a[0] = lo.x; a[1] = lo.y; a[2] = lo.z; a[3] = lo.w;
      a[4] = hi.x; a[5] = hi.y; a[6] = hi.z; a[7] = hi.w;
#pragma unroll
      for (int nt = 0; nt < 4; ++nt)
        acc[mt][nt] = mfma_mx(a, bfrag[nt], acc[mt][nt]);
    }
    __syncthreads();
  }

  // ---- fused epilogue: v = mask*(C*w_i - S); sum v^2 ----
  // C/D layout (shape-determined): col = lane&15, row = quad*4 + reg
  float local = 0.0f;
#pragma unroll
  for (int mt = 0; mt < 4; ++mt) {
    const int i0 = rowBase + wm * 64 + mt * 16 + quad * 4;
    float wr[4];
#pragma unroll
    for (int r = 0; r < 4; ++r) wr[r] = w[i0 + r];
#pragma unroll
    for (int nt = 0; nt < 4; ++nt) {
      const int col = colBase + wn * 64 + nt * 16 + l16;
      const int bb = col >> 8;
      const int dd = col & 255;
      const float* Sp = S + (size_t)bb * (N_NODES * DMODEL) + (size_t)i0 * DMODEL + dd;
#pragma unroll
      for (int r = 0; r < 4; ++r) {
        float v = acc[mt][nt][r] * wr[r] - Sp[(size_t)r * DMODEL];
        v = (wr[r] > 0.0f) ? v : 0.0f;
        local += v * v;
      }
    }
  }

#pragma unroll
  for (int off = 32; off > 0; off >>= 1) local += __shfl_down(local, off);
  if (lane == 0) wsum[wave] = local;
  __syncthreads();
  if (tid == 0)
    atomicAdd(out, (wsum[0] + wsum[1] + wsum[2] + wsum[3]) * INV_BND);
}

// ---------------------------------------------------------------------------
extern "C" void kernel_launch(void* const* d_in, const int* in_sizes, int n_in,
                              void* d_out, int out_size, void* d_ws, size_t ws_size,
                              hipStream_t stream) {
  const float* S  = (const float*)d_in[0];   // (8, 4096, 256) f32
  const int* adj  = (const int*)d_in[1];     // (4096, 4096) i32
  float* out = (float*)d_out;                // scalar f32

  // ws layout: A8 fp8 (16 MiB) | B8 fp8 (8 MiB) | w (16 KiB)
  unsigned char* A8 = (unsigned char*)d_ws;
  unsigned char* B8 = (unsigned char*)d_ws + (size_t)N_NODES * N_NODES;
  float* w = (float*)((char*)d_ws + (size_t)N_NODES * N_NODES + (size_t)NCOL * KDIM);

  // single prep dispatch: adj-blocks [0,4096), transpose-blocks [4096,6144)
  fat_prep<<<N_NODES + (N_NODES / 128) * (DMODEL / 32) * BATCH, 256, 0, stream>>>(
      adj, S, A8, B8, w, out);

  gemm_div<<<dim3(N_NODES / 128, NCOL / 128, 1), 256, 0, stream>>>(A8, B8, w, S, out);
}